// Round 6
// baseline (475.049 us; speedup 1.0000x reference)
//
#include <hip/hip_runtime.h>

#define KH 5
#define KW 5
#define CIN 16
#define NF 32
#define BATCH 4
#define H 224
#define W 224
#define HO 220
#define WO 220
#define RPB 4              // output rows per wave
#define XROWS (RPB + KH - 1)   // 8 input rows in the register window
#define WPAD 32            // taps padded 25 -> 32 floats (128 B) for s_load_dwordx16

// planar path: one 64-thread (1-wave) block per (oct, c, hoT, b)
#define NTILE (HO / RPB)                 // 55
#define NBLKP (4 * CIN * NTILE * BATCH)  // 14080; %8==0 -> bijective XCD swizzle
#define CPXP (NBLKP / 8)                 // 1760

// legacy fallback grid
#define NBLKL (CIN * NTILE * BATCH)      // 3520
#define CPXL (NBLKL / 8)                 // 440

#define XP_FLOATS ((size_t)CIN * BATCH * H * W)   // 3,211,264
#define WS_NEEDED (65536 + XP_FLOATS * 4)         // Wt (64 KB) + planar X

// ---- pre-kernel: transpose weights [tap][c][f] -> Wt[c][f][tap(pad 32)] ----
__global__ void transpose_weights(const float* __restrict__ Kw,
                                  float* __restrict__ Wt) {
    int idx = blockIdx.x * 256 + threadIdx.x;     // over KH*KW*CIN*NF = 12800
    if (idx < KH * KW * CIN * NF) {
        const int tap = idx / (CIN * NF);
        const int rem = idx - tap * (CIN * NF);
        const int c   = rem >> 5;                 // / NF
        const int f   = rem & 31;                 // % NF
        Wt[((size_t)(c * NF) + f) * WPAD + tap] = Kw[idx];
    }
}

// ---- pre-kernel: transpose input [B,H,W,C] -> planar Xp[C][B][H][W] ----
// one block per (h, b): stage the 224x16 row-slab in LDS (pitch 17 kills
// bank conflicts), read coalesced, write each c-plane's row coalesced.
__global__ __launch_bounds__(256) void transpose_input(
    const float* __restrict__ X, float* __restrict__ Xp)
{
    __shared__ float tile[W * 17];     // [w][c] pitch 17 = 15232 B
    const int h = blockIdx.x;
    const int b = blockIdx.y;
    const int t = threadIdx.x;
    const float* in = X + ((size_t)(b * H + h) * W) * CIN;
#pragma unroll
    for (int k = 0; k < W * CIN / 256; ++k) {     // 14 iters
        const int idx = k * 256 + t;              // = w*16 + c
        tile[(idx >> 4) * 17 + (idx & 15)] = in[idx];
    }
    __syncthreads();
#pragma unroll
    for (int k = 0; k < W * CIN / 256; ++k) {
        const int idx = k * 256 + t;
        const int c = idx / W;                    // 0..15
        const int w = idx - c * W;                // 0..223
        Xp[((uint32_t)(c * BATCH + b) * H + h) * W + w] = tile[w * 17 + c];
    }
}

// ---- planar conv: 1-wave blocks, no LDS, no barrier ----
// Window loads are 16 coalesced float4s from the planar rows; filter loop is
// the R4-proven structure (scalar FMA, 2-deep uniform s_load ping-pong).
// Math exact in fp32 (x < 256, |k| <= 8, sums < 2^24).
__device__ __forceinline__ void pcompute_store(
    const float (&xr)[XROWS][8], const float (&wk)[KH * KW],
    const uint32_t (&obase)[RPB], int f, float* __restrict__ O)
{
    float acc[RPB][4];
#pragma unroll
    for (int r = 0; r < RPB; ++r)
#pragma unroll
        for (int q = 0; q < 4; ++q) acc[r][q] = 0.0f;

#pragma unroll
    for (int i = 0; i < KH; ++i)
#pragma unroll
        for (int j = 0; j < KW; ++j) {
            const float w = wk[i * KW + j];
#pragma unroll
            for (int r = 0; r < RPB; ++r) {
                acc[r][0] += xr[r + i][j + 0] * w;
                acc[r][1] += xr[r + i][j + 1] * w;
                acc[r][2] += xr[r + i][j + 2] * w;
                acc[r][3] += xr[r + i][j + 3] * w;
            }
        }

#pragma unroll
    for (int r = 0; r < RPB; ++r)
        *(float4*)&O[obase[r] + (uint32_t)f * WO] =
            make_float4(acc[r][0], acc[r][1], acc[r][2], acc[r][3]);
}

__global__ __launch_bounds__(64, 4) void conv2d_planar(
    const float* __restrict__ Xp,   // [CIN][BATCH][H][W]
    const float* __restrict__ Wt,   // [CIN, NF, WPAD]
    float* __restrict__ O)          // [B, HO, CIN, NF, WO]
{
    // bijective XCD swizzle; logical order: oct, c, hoT, b (fastest->slowest)
    const int bid = blockIdx.x;
    const int l   = (bid & 7) * CPXP + (bid >> 3);
    const int oct = l & 3;
    const int c   = (l >> 2) & 15;
    const int rest = l >> 6;          // 0..219
    const int hoT = rest % NTILE;
    const int b   = rest / NTILE;
    const int ho0 = hoT * RPB;

    const int lane = threadIdx.x;     // single wave
    const int wo0  = lane * 4;
    if (lane >= 55) return;           // 55*4 = 220 = WO

    // register window: 8 rows x 8 floats, 16 coalesced float4 loads
    const uint32_t rbase = ((uint32_t)(c * BATCH + b) * H + ho0) * W + wo0;
    float xr[XROWS][8];
#pragma unroll
    for (int r = 0; r < XROWS; ++r) {
        const float4 xa = *(const float4*)&Xp[rbase + (uint32_t)r * W];
        const float4 xb = *(const float4*)&Xp[rbase + (uint32_t)r * W + 4];
        xr[r][0] = xa.x; xr[r][1] = xa.y; xr[r][2] = xa.z; xr[r][3] = xa.w;
        xr[r][4] = xb.x; xr[r][5] = xb.y; xr[r][6] = xb.z; xr[r][7] = xb.w;
    }

    uint32_t obase[RPB];
#pragma unroll
    for (int r = 0; r < RPB; ++r)
        obase[r] = (((uint32_t)(b * HO + ho0 + r) * CIN + c) * NF) * WO + wo0;

    const float* wc = Wt + (size_t)(c * NF) * WPAD;
    const int f0 = oct * 8;           // wave-uniform (SGPR) by construction

    float wkA[KH * KW], wkB[KH * KW];
    {
        const float* wp = wc + (size_t)f0 * WPAD;
#pragma unroll
        for (int tap = 0; tap < KH * KW; ++tap) wkA[tap] = wp[tap];
    }

#pragma unroll 1
    for (int fi = 0; fi < 8; fi += 2) {
        {
            const float* wp = wc + (size_t)(f0 + fi + 1) * WPAD;
#pragma unroll
            for (int tap = 0; tap < KH * KW; ++tap) wkB[tap] = wp[tap];
        }
        pcompute_store(xr, wkA, obase, f0 + fi, O);
        {
            const float* wp = wc + (size_t)(f0 + ((fi + 2) & 7)) * WPAD;
#pragma unroll
            for (int tap = 0; tap < KH * KW; ++tap) wkA[tap] = wp[tap];
        }
        pcompute_store(xr, wkB, obase, f0 + fi + 1, O);
    }
}

// ---- legacy fallback (R4, measured 408 us total): used if ws too small ----
__global__ __launch_bounds__(256) void conv2d_legacy(
    const float* __restrict__ X,    // [B, H, W, CIN]
    const float* __restrict__ Wt,
    float* __restrict__ O)
{
    __shared__ float xs[XROWS * W];

    const int bid = blockIdx.x;
    const int l   = (bid & 7) * CPXL + (bid >> 3);
    const int c   = l & 15;
    const int rest = l >> 4;
    const int hoT = rest % NTILE;
    const int b   = rest / NTILE;
    const int ho0 = hoT * RPB;
    const int t   = threadIdx.x;

    const uint32_t xoff = ((uint32_t)(b * H + ho0) * W) * CIN + c;
#pragma unroll
    for (int k = 0; k < XROWS * W / 256; ++k) {
        const int idx = t + k * 256;
        xs[idx] = X[xoff + (uint32_t)idx * CIN];
    }
    __syncthreads();

    const int wave = t >> 6;
    const int lane = t & 63;
    const int wo0  = lane * 4;
    if (lane >= 55) return;

    float xr[XROWS][8];
#pragma unroll
    for (int r = 0; r < XROWS; ++r) {
        const float4 xa = *(const float4*)&xs[r * W + wo0];
        const float4 xb = *(const float4*)&xs[r * W + wo0 + 4];
        xr[r][0] = xa.x; xr[r][1] = xa.y; xr[r][2] = xa.z; xr[r][3] = xa.w;
        xr[r][4] = xb.x; xr[r][5] = xb.y; xr[r][6] = xb.z; xr[r][7] = xb.w;
    }

    uint32_t obase[RPB];
#pragma unroll
    for (int r = 0; r < RPB; ++r)
        obase[r] = (((uint32_t)(b * HO + ho0 + r) * CIN + c) * NF) * WO + wo0;

    const float* wc = Wt + (size_t)(c * NF) * WPAD;
    const int f0 = __builtin_amdgcn_readfirstlane(wave * 8);

    float wkA[KH * KW], wkB[KH * KW];
    {
        const float* wp = wc + (size_t)f0 * WPAD;
#pragma unroll
        for (int tap = 0; tap < KH * KW; ++tap) wkA[tap] = wp[tap];
    }

#pragma unroll 1
    for (int fi = 0; fi < 8; fi += 2) {
        {
            const float* wp = wc + (size_t)(f0 + fi + 1) * WPAD;
#pragma unroll
            for (int tap = 0; tap < KH * KW; ++tap) wkB[tap] = wp[tap];
        }
        pcompute_store(xr, wkA, obase, f0 + fi, O);
        {
            const float* wp = wc + (size_t)(f0 + ((fi + 2) & 7)) * WPAD;
#pragma unroll
            for (int tap = 0; tap < KH * KW; ++tap) wkA[tap] = wp[tap];
        }
        pcompute_store(xr, wkB, obase, f0 + fi + 1, O);
    }
}

extern "C" void kernel_launch(void* const* d_in, const int* in_sizes, int n_in,
                              void* d_out, int out_size, void* d_ws, size_t ws_size,
                              hipStream_t stream) {
    const float* X  = (const float*)d_in[0];
    const float* Kw = (const float*)d_in[1];
    float* O        = (float*)d_out;
    float* Wt       = (float*)d_ws;                       // 64 KB
    float* Xp       = (float*)((char*)d_ws + 65536);      // 12.85 MB planar X

    transpose_weights<<<dim3(50), 256, 0, stream>>>(Kw, Wt);
    if (ws_size >= WS_NEEDED) {
        transpose_input<<<dim3(H, BATCH), 256, 0, stream>>>(X, Xp);
        conv2d_planar<<<dim3(NBLKP), 64, 0, stream>>>(Xp, Wt, O);
    } else {
        conv2d_legacy<<<dim3(NBLKL), 256, 0, stream>>>(X, Wt, O);
    }
}